// Round 9
// baseline (1107.816 us; speedup 1.0000x reference)
//
#include <hip/hip_runtime.h>

#define NB 2
#define D 32
#define H 128
#define NSTEPS 8
#define BT 1024   // 16 waves/block; 2 blocks/CU -> 32 waves/CU (max occupancy)

typedef _Float16 f16;
typedef _Float16 f16x2 __attribute__((ext_vector_type(2)));
typedef _Float16 f16x8 __attribute__((ext_vector_type(8)));
typedef float    f32x4 __attribute__((ext_vector_type(4)));
typedef unsigned int uint;

__device__ __forceinline__ float fast_tanh(float v) {
    // tanh(v) = 1 - 2/(1+2^(v*2log2e)); exp2 saturates -> exact +-1 limits.
    float e = __builtin_amdgcn_exp2f(v * 2.8853900817779268f);
    return 1.f - 2.f * __builtin_amdgcn_rcpf(1.f + e);
}
// tanh two f32 accs -> packed f16x2 dword
__device__ __forceinline__ uint tanh_pk(float a, float b) {
    return __builtin_bit_cast(uint, __builtin_amdgcn_cvt_pkrtz(fast_tanh(a), fast_tanh(b)));
}
__device__ __forceinline__ uint pku(float a, float b) {
    return __builtin_bit_cast(uint, __builtin_amdgcn_cvt_pkrtz(a, b));
}
__device__ __forceinline__ float lo32(uint u) { return (float)__builtin_bit_cast(f16x2, u)[0]; }
__device__ __forceinline__ float hi32(uint u) { return (float)__builtin_bit_cast(f16x2, u)[1]; }

__device__ const float CC[6] = {0.f, 0.2f, 0.3f, 0.8f, 8.f/9.f, 1.f};

// LDS: weights only, fragment-ordered & k-permuted. ~50 KB -> 2 blocks/CU fit.
struct __align__(16) SMem {
    f16   W1f[8 * 64 * 8];     // [nt][lane][j]      : W1[32+phi1(q,j)][nt*16+mr]
    f16   W2f[8 * 4 * 64 * 8]; // [nt][kt][lane][j]  : W2[phi(kt,q,j)][nt*16+mr]
    f16   W3f[2 * 4 * 64 * 8]; // [nt][kt][lane][j]  : W3[phi(kt,q,j)][nt*16+mr]
    float B1[H], S1[H], B2[H], B3[D];
};

// phi(kt,q,j) = (2kt + j/4)*16 + q*4 + j%4 ; phi1(q,j) = (j/4)*16 + q*4 + j%4.
// Identical k-permutation on A (staged weights) and B (C-layout activations)
// -> MFMA k-sum invariant. Zero activation LDS traffic, zero shuffles.
//
// REGISTER-PRESSURE RULES (measured R3..R8):
//  * launch_bounds waves/EU sets unified budget = 2048/waves: (256,2) & (1024,8)
//    -> 256 unified -> 128 arch VGPRs; (256,3) -> 84 arch -> 12 GB spill (R6).
//  * nt-loops MUST be `#pragma unroll 1`: full unroll hoists all ds_read_b128
//    weight loads (layer 2: 32 in flight = 128 VGPRs) -> GB-scale scratch spill
//    (R4: 7.4 GB, R7: 7.6 GB). R8 with unroll 1: zero spill, VGPR=76.
//  * 1024-thread block (R9): same 256-unified/wave budget, but 16 waves/block
//    x 2 blocks/CU = 32 waves/CU vs R8's 8 -> fills VALU issue gaps (71%->goal 95%).

__global__ __launch_bounds__(BT, 8) void ffjord_mfma(
    const float* __restrict__ x_in,
    const float* __restrict__ W1, const float* __restrict__ b1,
    const float* __restrict__ W2, const float* __restrict__ b2,
    const float* __restrict__ W3, const float* __restrict__ b3,
    float* __restrict__ out)
{
    __shared__ SMem sm;

    const int tid  = threadIdx.x;
    const int lane = tid & 63;
    const int mrow = lane & 15;      // my sample within the wave tile
    const int quad = lane >> 4;      // k/feature quad
    const int wid  = tid >> 6;       // wave id 0..15
    const int sidx = blockIdx.x * (BT/4) + wid * 16 + mrow;  // my sample (global)

    // Distributed state: x[nt*4 + r] = value[feature nt*16+quad*4+r][sample sidx]
    // k1..k5 packed f16x2: ksp[i][j] holds (elem 2j, 2j+1).
    float x[8];
    uint  ksp[5][4];
    uint  by[4];      // packed f16 y — layer-1 B fragment (IS the eval input)

    #pragma unroll
    for (int nt = 0; nt < 2; ++nt) {
        f32x4 v = *(const f32x4*)(x_in + (size_t)sidx*D + nt*16 + quad*4);
        #pragma unroll
        for (int r = 0; r < 4; ++r) x[nt*4 + r] = v[r];
    }

    const float dt = 0.125f;

    for (int bij = 0; bij < NB; ++bij) {
        const float* W1b = W1 + (size_t)bij * 2*D*H;
        const float* b1b = b1 + bij*H;
        const float* W2b = W2 + (size_t)bij * H*H;
        const float* b2b = b2 + bij*H;
        const float* W3b = W3 + (size_t)bij * H*D;
        const float* b3b = b3 + bij*D;

        __syncthreads();  // prior bijector done reading weights
        // ---- stage weights: fragment-order, k-permuted, f16 ----
        #pragma unroll 1
        for (int g = tid; g < 8*64; g += BT) {               // W1f
            int nt = g >> 6, ln = g & 63, q = (ln >> 4) & 3, mr = ln & 15;
            f16 tmp[8];
            #pragma unroll
            for (int j = 0; j < 8; ++j) {
                int feat = ((j >> 2) << 4) + q*4 + (j & 3);  // phi1
                tmp[j] = (f16)W1b[(size_t)(D + feat)*H + nt*16 + mr];
            }
            *(f16x8*)&sm.W1f[(size_t)g * 8] = *(f16x8*)tmp;
        }
        #pragma unroll 1
        for (int g = tid; g < 8*4*64; g += BT) {             // W2f
            int nt = g >> 8, kt = (g >> 6) & 3, ln = g & 63, q = (ln >> 4) & 3, mr = ln & 15;
            f16 tmp[8];
            #pragma unroll
            for (int j = 0; j < 8; ++j) {
                int feat = (2*kt + (j >> 2))*16 + q*4 + (j & 3);  // phi
                tmp[j] = (f16)W2b[(size_t)feat*H + nt*16 + mr];
            }
            *(f16x8*)&sm.W2f[(size_t)g * 8] = *(f16x8*)tmp;
        }
        #pragma unroll 1
        for (int g = tid; g < 2*4*64; g += BT) {             // W3f
            int nt = g >> 8, kt = (g >> 6) & 3, ln = g & 63, q = (ln >> 4) & 3, mr = ln & 15;
            f16 tmp[8];
            #pragma unroll
            for (int j = 0; j < 8; ++j) {
                int feat = (2*kt + (j >> 2))*16 + q*4 + (j & 3);  // phi
                tmp[j] = (f16)W3b[(size_t)feat*D + nt*16 + mr];
            }
            *(f16x8*)&sm.W3f[(size_t)g * 8] = *(f16x8*)tmp;
        }
        #pragma unroll 1
        for (int n = tid; n < H; n += BT) {                  // biases + t-fold sums
            float s = 0.f;
            for (int i = 0; i < D; ++i) s += W1b[(size_t)i*H + n];
            sm.S1[n] = s; sm.B1[n] = b1b[n]; sm.B2[n] = b2b[n];
        }
        if (tid < D) sm.B3[tid] = b3b[tid];
        __syncthreads();

        // y := x  (packed)
        #pragma unroll
        for (int p = 0; p < 4; ++p)
            by[p] = pku(x[2*p], x[2*p + 1]);

        for (int step = 0; step < NSTEPS; ++step) {
            const float t0 = step * dt;
            #pragma unroll 1
            for (int s = 0; s < 6; ++s) {
                const float te = t0 + dt * CC[s];

                // ============ EVAL (registers + conflict-free weight LDS) ============
                // layer 1 (K=32): C init = b1 + te*S1 (t-concat folded into bias)
                uint ph1[16];
                {
                    union { f16x8 v; uint u[4]; } b;
                    b.u[0] = by[0]; b.u[1] = by[1]; b.u[2] = by[2]; b.u[3] = by[3];
                    #pragma unroll 1
                    for (int nt = 0; nt < 8; ++nt) {
                        f16x8 wf = *(const f16x8*)&sm.W1f[(nt*64 + lane)*8];
                        f32x4 bv = *(const f32x4*)&sm.B1[nt*16 + quad*4];
                        f32x4 sv = *(const f32x4*)&sm.S1[nt*16 + quad*4];
                        f32x4 ci;
                        #pragma unroll
                        for (int r = 0; r < 4; ++r) ci[r] = fmaf(te, sv[r], bv[r]);
                        f32x4 acc = __builtin_amdgcn_mfma_f32_16x16x32_f16(wf, b.v, ci, 0, 0, 0);
                        ph1[nt*2+0] = tanh_pk(acc[0], acc[1]);
                        ph1[nt*2+1] = tanh_pk(acc[2], acc[3]);
                    }
                }
                // layer 2 (K=128): B = ph1 dwords (phi-matched)
                uint ph2[16];
                #pragma unroll 1
                for (int nt = 0; nt < 8; ++nt) {
                    f32x4 acc = *(const f32x4*)&sm.B2[nt*16 + quad*4];
                    #pragma unroll
                    for (int kt = 0; kt < 4; ++kt) {
                        f16x8 wf = *(const f16x8*)&sm.W2f[((nt*4 + kt)*64 + lane)*8];
                        union { f16x8 v; uint u[4]; } b;
                        b.u[0] = ph1[kt*4+0]; b.u[1] = ph1[kt*4+1];
                        b.u[2] = ph1[kt*4+2]; b.u[3] = ph1[kt*4+3];
                        acc = __builtin_amdgcn_mfma_f32_16x16x32_f16(wf, b.v, acc, 0, 0, 0);
                    }
                    ph2[nt*2+0] = tanh_pk(acc[0], acc[1]);
                    ph2[nt*2+1] = tanh_pk(acc[2], acc[3]);
                }
                // layer 3 (K=128, Nout=32): kd lands in distributed layout
                float kd[8];
                #pragma unroll 1
                for (int nt = 0; nt < 2; ++nt) {
                    f32x4 acc = *(const f32x4*)&sm.B3[nt*16 + quad*4];
                    #pragma unroll
                    for (int kt = 0; kt < 4; ++kt) {
                        f16x8 wf = *(const f16x8*)&sm.W3f[((nt*4 + kt)*64 + lane)*8];
                        union { f16x8 v; uint u[4]; } b;
                        b.u[0] = ph2[kt*4+0]; b.u[1] = ph2[kt*4+1];
                        b.u[2] = ph2[kt*4+2]; b.u[3] = ph2[kt*4+3];
                        acc = __builtin_amdgcn_mfma_f32_16x16x32_f16(wf, b.v, acc, 0, 0, 0);
                    }
                    #pragma unroll
                    for (int r = 0; r < 4; ++r) kd[nt*4 + r] = acc[r];
                }

                // ===== DOPRI combine; k-history packed f16, y kept only packed =====
                switch (s) {
                case 0:
                    #pragma unroll
                    for (int j = 0; j < 4; ++j) {
                        ksp[0][j] = pku(kd[2*j], kd[2*j+1]);
                        float ya = fmaf(dt*0.2f, kd[2*j],   x[2*j]);
                        float yb = fmaf(dt*0.2f, kd[2*j+1], x[2*j+1]);
                        by[j] = pku(ya, yb);
                    }
                    break;
                case 1:
                    #pragma unroll
                    for (int j = 0; j < 4; ++j) {
                        ksp[1][j] = pku(kd[2*j], kd[2*j+1]);
                        float ya = x[2*j]   + dt*((3.f/40.f)*lo32(ksp[0][j]) + (9.f/40.f)*kd[2*j]);
                        float yb = x[2*j+1] + dt*((3.f/40.f)*hi32(ksp[0][j]) + (9.f/40.f)*kd[2*j+1]);
                        by[j] = pku(ya, yb);
                    }
                    break;
                case 2:
                    #pragma unroll
                    for (int j = 0; j < 4; ++j) {
                        ksp[2][j] = pku(kd[2*j], kd[2*j+1]);
                        float ya = x[2*j]   + dt*((44.f/45.f)*lo32(ksp[0][j]) - (56.f/15.f)*lo32(ksp[1][j]) + (32.f/9.f)*kd[2*j]);
                        float yb = x[2*j+1] + dt*((44.f/45.f)*hi32(ksp[0][j]) - (56.f/15.f)*hi32(ksp[1][j]) + (32.f/9.f)*kd[2*j+1]);
                        by[j] = pku(ya, yb);
                    }
                    break;
                case 3:
                    #pragma unroll
                    for (int j = 0; j < 4; ++j) {
                        ksp[3][j] = pku(kd[2*j], kd[2*j+1]);
                        float ya = x[2*j]   + dt*((19372.f/6561.f)*lo32(ksp[0][j]) - (25360.f/2187.f)*lo32(ksp[1][j])
                                                + (64448.f/6561.f)*lo32(ksp[2][j]) - (212.f/729.f)*kd[2*j]);
                        float yb = x[2*j+1] + dt*((19372.f/6561.f)*hi32(ksp[0][j]) - (25360.f/2187.f)*hi32(ksp[1][j])
                                                + (64448.f/6561.f)*hi32(ksp[2][j]) - (212.f/729.f)*kd[2*j+1]);
                        by[j] = pku(ya, yb);
                    }
                    break;
                case 4:
                    #pragma unroll
                    for (int j = 0; j < 4; ++j) {
                        ksp[4][j] = pku(kd[2*j], kd[2*j+1]);
                        float ya = x[2*j]   + dt*((9017.f/3168.f)*lo32(ksp[0][j]) - (355.f/33.f)*lo32(ksp[1][j])
                                                + (46732.f/5247.f)*lo32(ksp[2][j]) + (49.f/176.f)*lo32(ksp[3][j])
                                                - (5103.f/18656.f)*kd[2*j]);
                        float yb = x[2*j+1] + dt*((9017.f/3168.f)*hi32(ksp[0][j]) - (355.f/33.f)*hi32(ksp[1][j])
                                                + (46732.f/5247.f)*hi32(ksp[2][j]) + (49.f/176.f)*hi32(ksp[3][j])
                                                - (5103.f/18656.f)*kd[2*j+1]);
                        by[j] = pku(ya, yb);
                    }
                    break;
                default:
                    #pragma unroll
                    for (int j = 0; j < 4; ++j) {
                        float xa = x[2*j]   + dt*((35.f/384.f)*lo32(ksp[0][j]) + (500.f/1113.f)*lo32(ksp[2][j])
                                                + (125.f/192.f)*lo32(ksp[3][j]) - (2187.f/6784.f)*lo32(ksp[4][j])
                                                + (11.f/84.f)*kd[2*j]);
                        float xb = x[2*j+1] + dt*((35.f/384.f)*hi32(ksp[0][j]) + (500.f/1113.f)*hi32(ksp[2][j])
                                                + (125.f/192.f)*hi32(ksp[3][j]) - (2187.f/6784.f)*hi32(ksp[4][j])
                                                + (11.f/84.f)*kd[2*j+1]);
                        x[2*j] = xa; x[2*j+1] = xb;
                        by[j] = pku(xa, xb);
                    }
                    break;
                }
            } // stages
        } // steps
    } // bijectors

    #pragma unroll
    for (int nt = 0; nt < 2; ++nt) {
        f32x4 v;
        #pragma unroll
        for (int r = 0; r < 4; ++r) v[r] = x[nt*4 + r];
        *(f32x4*)(out + (size_t)sidx*D + nt*16 + quad*4) = v;
    }
}

extern "C" void kernel_launch(void* const* d_in, const int* in_sizes, int n_in,
                              void* d_out, int out_size, void* d_ws, size_t ws_size,
                              hipStream_t stream) {
    (void)d_ws; (void)ws_size; (void)n_in; (void)out_size;
    const float* x  = (const float*)d_in[0];
    const float* W1 = (const float*)d_in[1];
    const float* b1 = (const float*)d_in[2];
    const float* W2 = (const float*)d_in[3];
    const float* b2 = (const float*)d_in[4];
    const float* W3 = (const float*)d_in[5];
    const float* b3 = (const float*)d_in[6];
    float* out = (float*)d_out;

    const int n = in_sizes[0] / D;          // 65536 samples
    const int grid = n / (BT/4);            // 256 blocks of 1024 thr (256 samples)
    ffjord_mfma<<<grid, BT, 0, stream>>>(x, W1, b1, W2, b2, W3, b3, out);
}

// Round 10
// 908.992 us; speedup vs baseline: 1.2187x; 1.2187x over previous
//
#include <hip/hip_runtime.h>

#define NB 2
#define D 32
#define H 128
#define NSTEPS 8
#define BT 256

typedef _Float16 f16;
typedef _Float16 f16x2 __attribute__((ext_vector_type(2)));
typedef _Float16 f16x8 __attribute__((ext_vector_type(8)));
typedef float    f32x4 __attribute__((ext_vector_type(4)));
typedef unsigned int uint;

__device__ __forceinline__ float fast_tanh(float v) {
    // tanh(v) = 1 - 2/(1+2^(v*2log2e)); exp2 saturates -> exact +-1 limits.
    float e = __builtin_amdgcn_exp2f(v * 2.8853900817779268f);
    return 1.f - 2.f * __builtin_amdgcn_rcpf(1.f + e);
}
// tanh two f32 accs -> packed f16x2 dword
__device__ __forceinline__ uint tanh_pk(float a, float b) {
    return __builtin_bit_cast(uint, __builtin_amdgcn_cvt_pkrtz(fast_tanh(a), fast_tanh(b)));
}
__device__ __forceinline__ uint pku(float a, float b) {
    return __builtin_bit_cast(uint, __builtin_amdgcn_cvt_pkrtz(a, b));
}
__device__ __forceinline__ float lo32(uint u) { return (float)__builtin_bit_cast(f16x2, u)[0]; }
__device__ __forceinline__ float hi32(uint u) { return (float)__builtin_bit_cast(f16x2, u)[1]; }

__device__ const float CC[6] = {0.f, 0.2f, 0.3f, 0.8f, 8.f/9.f, 1.f};

// LDS: weights only, fragment-ordered & k-permuted. ~50 KB -> 3 blocks/CU fit.
struct __align__(16) SMem {
    f16   W1f[8 * 64 * 8];     // [nt][lane][j]      : W1[32+phi1(q,j)][nt*16+mr]
    f16   W2f[8 * 4 * 64 * 8]; // [nt][kt][lane][j]  : W2[phi(kt,q,j)][nt*16+mr]
    f16   W3f[2 * 4 * 64 * 8]; // [nt][kt][lane][j]  : W3[phi(kt,q,j)][nt*16+mr]
    float B1[H], S1[H], B2[H], B3[D];
};

// phi(kt,q,j) = (2kt + j/4)*16 + q*4 + j%4 ; phi1(q,j) = (j/4)*16 + q*4 + j%4.
// Identical k-permutation on A (staged weights) and B (C-layout activations)
// -> MFMA k-sum invariant. Zero activation LDS traffic, zero shuffles.
//
// REGISTER-PRESSURE MODEL (measured R3..R9, now consistent):
//  * per-SIMD VGPR pool = 512; __launch_bounds__(_,w) -> unified budget 512/w
//    per wave; arch cap ~= budget/2. (256,2)->128 arch; (256,3)->84; (1024,8)->32
//    (R9: starved, 3.8 GB spill, 1108 us).
//  * nt-loops MUST be `#pragma unroll 1`: full unroll hoists all ds_read_b128
//    weight loads (layer 2: 32 in flight = 128 VGPRs) -> GB-scale scratch spill
//    (R4: 7.4 GB, R7: 7.6 GB). R8 with unroll 1: zero spill, VGPR=76.
//  * R10: (256,3) -> 84-arch cap >= 76 used -> 12 waves/CU (3 blocks, LDS-exact).

__global__ __launch_bounds__(BT, 3) void ffjord_mfma(
    const float* __restrict__ x_in,
    const float* __restrict__ W1, const float* __restrict__ b1,
    const float* __restrict__ W2, const float* __restrict__ b2,
    const float* __restrict__ W3, const float* __restrict__ b3,
    float* __restrict__ out)
{
    __shared__ SMem sm;

    const int tid  = threadIdx.x;
    const int lane = tid & 63;
    const int mrow = lane & 15;      // my sample within the wave tile
    const int quad = lane >> 4;      // k/feature quad
    const int wid  = tid >> 6;
    const int sidx = blockIdx.x * 64 + wid * 16 + mrow;   // my sample (global)

    // Distributed state: x[nt*4 + r] = value[feature nt*16+quad*4+r][sample sidx]
    // k1..k5 packed f16x2: ksp[i][j] holds (elem 2j, 2j+1).
    float x[8];
    uint  ksp[5][4];
    uint  by[4];      // packed f16 y — layer-1 B fragment (IS the eval input)

    #pragma unroll
    for (int nt = 0; nt < 2; ++nt) {
        f32x4 v = *(const f32x4*)(x_in + (size_t)sidx*D + nt*16 + quad*4);
        #pragma unroll
        for (int r = 0; r < 4; ++r) x[nt*4 + r] = v[r];
    }

    const float dt = 0.125f;

    for (int bij = 0; bij < NB; ++bij) {
        const float* W1b = W1 + (size_t)bij * 2*D*H;
        const float* b1b = b1 + bij*H;
        const float* W2b = W2 + (size_t)bij * H*H;
        const float* b2b = b2 + bij*H;
        const float* W3b = W3 + (size_t)bij * H*D;
        const float* b3b = b3 + bij*D;

        __syncthreads();  // prior bijector done reading weights
        // ---- stage weights: fragment-order, k-permuted, f16 ----
        #pragma unroll 1
        for (int g = tid; g < 8*64; g += BT) {               // W1f
            int nt = g >> 6, ln = g & 63, q = (ln >> 4) & 3, mr = ln & 15;
            f16 tmp[8];
            #pragma unroll
            for (int j = 0; j < 8; ++j) {
                int feat = ((j >> 2) << 4) + q*4 + (j & 3);  // phi1
                tmp[j] = (f16)W1b[(size_t)(D + feat)*H + nt*16 + mr];
            }
            *(f16x8*)&sm.W1f[(size_t)g * 8] = *(f16x8*)tmp;
        }
        #pragma unroll 1
        for (int g = tid; g < 8*4*64; g += BT) {             // W2f
            int nt = g >> 8, kt = (g >> 6) & 3, ln = g & 63, q = (ln >> 4) & 3, mr = ln & 15;
            f16 tmp[8];
            #pragma unroll
            for (int j = 0; j < 8; ++j) {
                int feat = (2*kt + (j >> 2))*16 + q*4 + (j & 3);  // phi
                tmp[j] = (f16)W2b[(size_t)feat*H + nt*16 + mr];
            }
            *(f16x8*)&sm.W2f[(size_t)g * 8] = *(f16x8*)tmp;
        }
        #pragma unroll 1
        for (int g = tid; g < 2*4*64; g += BT) {             // W3f
            int nt = g >> 8, kt = (g >> 6) & 3, ln = g & 63, q = (ln >> 4) & 3, mr = ln & 15;
            f16 tmp[8];
            #pragma unroll
            for (int j = 0; j < 8; ++j) {
                int feat = (2*kt + (j >> 2))*16 + q*4 + (j & 3);  // phi
                tmp[j] = (f16)W3b[(size_t)feat*D + nt*16 + mr];
            }
            *(f16x8*)&sm.W3f[(size_t)g * 8] = *(f16x8*)tmp;
        }
        #pragma unroll 1
        for (int n = tid; n < H; n += BT) {                  // biases + t-fold sums
            float s = 0.f;
            for (int i = 0; i < D; ++i) s += W1b[(size_t)i*H + n];
            sm.S1[n] = s; sm.B1[n] = b1b[n]; sm.B2[n] = b2b[n];
        }
        if (tid < D) sm.B3[tid] = b3b[tid];
        __syncthreads();

        // y := x  (packed)
        #pragma unroll
        for (int p = 0; p < 4; ++p)
            by[p] = pku(x[2*p], x[2*p + 1]);

        for (int step = 0; step < NSTEPS; ++step) {
            const float t0 = step * dt;
            #pragma unroll 1
            for (int s = 0; s < 6; ++s) {
                const float te = t0 + dt * CC[s];

                // ============ EVAL (registers + conflict-free weight LDS) ============
                // layer 1 (K=32): C init = b1 + te*S1 (t-concat folded into bias)
                uint ph1[16];
                {
                    union { f16x8 v; uint u[4]; } b;
                    b.u[0] = by[0]; b.u[1] = by[1]; b.u[2] = by[2]; b.u[3] = by[3];
                    #pragma unroll 1
                    for (int nt = 0; nt < 8; ++nt) {
                        f16x8 wf = *(const f16x8*)&sm.W1f[(nt*64 + lane)*8];
                        f32x4 bv = *(const f32x4*)&sm.B1[nt*16 + quad*4];
                        f32x4 sv = *(const f32x4*)&sm.S1[nt*16 + quad*4];
                        f32x4 ci;
                        #pragma unroll
                        for (int r = 0; r < 4; ++r) ci[r] = fmaf(te, sv[r], bv[r]);
                        f32x4 acc = __builtin_amdgcn_mfma_f32_16x16x32_f16(wf, b.v, ci, 0, 0, 0);
                        ph1[nt*2+0] = tanh_pk(acc[0], acc[1]);
                        ph1[nt*2+1] = tanh_pk(acc[2], acc[3]);
                    }
                }
                // layer 2 (K=128): B = ph1 dwords (phi-matched)
                uint ph2[16];
                #pragma unroll 1
                for (int nt = 0; nt < 8; ++nt) {
                    f32x4 acc = *(const f32x4*)&sm.B2[nt*16 + quad*4];
                    #pragma unroll
                    for (int kt = 0; kt < 4; ++kt) {
                        f16x8 wf = *(const f16x8*)&sm.W2f[((nt*4 + kt)*64 + lane)*8];
                        union { f16x8 v; uint u[4]; } b;
                        b.u[0] = ph1[kt*4+0]; b.u[1] = ph1[kt*4+1];
                        b.u[2] = ph1[kt*4+2]; b.u[3] = ph1[kt*4+3];
                        acc = __builtin_amdgcn_mfma_f32_16x16x32_f16(wf, b.v, acc, 0, 0, 0);
                    }
                    ph2[nt*2+0] = tanh_pk(acc[0], acc[1]);
                    ph2[nt*2+1] = tanh_pk(acc[2], acc[3]);
                }
                // layer 3 (K=128, Nout=32): kd lands in distributed layout
                float kd[8];
                #pragma unroll 1
                for (int nt = 0; nt < 2; ++nt) {
                    f32x4 acc = *(const f32x4*)&sm.B3[nt*16 + quad*4];
                    #pragma unroll
                    for (int kt = 0; kt < 4; ++kt) {
                        f16x8 wf = *(const f16x8*)&sm.W3f[((nt*4 + kt)*64 + lane)*8];
                        union { f16x8 v; uint u[4]; } b;
                        b.u[0] = ph2[kt*4+0]; b.u[1] = ph2[kt*4+1];
                        b.u[2] = ph2[kt*4+2]; b.u[3] = ph2[kt*4+3];
                        acc = __builtin_amdgcn_mfma_f32_16x16x32_f16(wf, b.v, acc, 0, 0, 0);
                    }
                    #pragma unroll
                    for (int r = 0; r < 4; ++r) kd[nt*4 + r] = acc[r];
                }

                // ===== DOPRI combine; k-history packed f16, y kept only packed =====
                switch (s) {
                case 0:
                    #pragma unroll
                    for (int j = 0; j < 4; ++j) {
                        ksp[0][j] = pku(kd[2*j], kd[2*j+1]);
                        float ya = fmaf(dt*0.2f, kd[2*j],   x[2*j]);
                        float yb = fmaf(dt*0.2f, kd[2*j+1], x[2*j+1]);
                        by[j] = pku(ya, yb);
                    }
                    break;
                case 1:
                    #pragma unroll
                    for (int j = 0; j < 4; ++j) {
                        ksp[1][j] = pku(kd[2*j], kd[2*j+1]);
                        float ya = x[2*j]   + dt*((3.f/40.f)*lo32(ksp[0][j]) + (9.f/40.f)*kd[2*j]);
                        float yb = x[2*j+1] + dt*((3.f/40.f)*hi32(ksp[0][j]) + (9.f/40.f)*kd[2*j+1]);
                        by[j] = pku(ya, yb);
                    }
                    break;
                case 2:
                    #pragma unroll
                    for (int j = 0; j < 4; ++j) {
                        ksp[2][j] = pku(kd[2*j], kd[2*j+1]);
                        float ya = x[2*j]   + dt*((44.f/45.f)*lo32(ksp[0][j]) - (56.f/15.f)*lo32(ksp[1][j]) + (32.f/9.f)*kd[2*j]);
                        float yb = x[2*j+1] + dt*((44.f/45.f)*hi32(ksp[0][j]) - (56.f/15.f)*hi32(ksp[1][j]) + (32.f/9.f)*kd[2*j+1]);
                        by[j] = pku(ya, yb);
                    }
                    break;
                case 3:
                    #pragma unroll
                    for (int j = 0; j < 4; ++j) {
                        ksp[3][j] = pku(kd[2*j], kd[2*j+1]);
                        float ya = x[2*j]   + dt*((19372.f/6561.f)*lo32(ksp[0][j]) - (25360.f/2187.f)*lo32(ksp[1][j])
                                                + (64448.f/6561.f)*lo32(ksp[2][j]) - (212.f/729.f)*kd[2*j]);
                        float yb = x[2*j+1] + dt*((19372.f/6561.f)*hi32(ksp[0][j]) - (25360.f/2187.f)*hi32(ksp[1][j])
                                                + (64448.f/6561.f)*hi32(ksp[2][j]) - (212.f/729.f)*kd[2*j+1]);
                        by[j] = pku(ya, yb);
                    }
                    break;
                case 4:
                    #pragma unroll
                    for (int j = 0; j < 4; ++j) {
                        ksp[4][j] = pku(kd[2*j], kd[2*j+1]);
                        float ya = x[2*j]   + dt*((9017.f/3168.f)*lo32(ksp[0][j]) - (355.f/33.f)*lo32(ksp[1][j])
                                                + (46732.f/5247.f)*lo32(ksp[2][j]) + (49.f/176.f)*lo32(ksp[3][j])
                                                - (5103.f/18656.f)*kd[2*j]);
                        float yb = x[2*j+1] + dt*((9017.f/3168.f)*hi32(ksp[0][j]) - (355.f/33.f)*hi32(ksp[1][j])
                                                + (46732.f/5247.f)*hi32(ksp[2][j]) + (49.f/176.f)*hi32(ksp[3][j])
                                                - (5103.f/18656.f)*kd[2*j+1]);
                        by[j] = pku(ya, yb);
                    }
                    break;
                default:
                    #pragma unroll
                    for (int j = 0; j < 4; ++j) {
                        float xa = x[2*j]   + dt*((35.f/384.f)*lo32(ksp[0][j]) + (500.f/1113.f)*lo32(ksp[2][j])
                                                + (125.f/192.f)*lo32(ksp[3][j]) - (2187.f/6784.f)*lo32(ksp[4][j])
                                                + (11.f/84.f)*kd[2*j]);
                        float xb = x[2*j+1] + dt*((35.f/384.f)*hi32(ksp[0][j]) + (500.f/1113.f)*hi32(ksp[2][j])
                                                + (125.f/192.f)*hi32(ksp[3][j]) - (2187.f/6784.f)*hi32(ksp[4][j])
                                                + (11.f/84.f)*kd[2*j+1]);
                        x[2*j] = xa; x[2*j+1] = xb;
                        by[j] = pku(xa, xb);
                    }
                    break;
                }
            } // stages
        } // steps
    } // bijectors

    #pragma unroll
    for (int nt = 0; nt < 2; ++nt) {
        f32x4 v;
        #pragma unroll
        for (int r = 0; r < 4; ++r) v[r] = x[nt*4 + r];
        *(f32x4*)(out + (size_t)sidx*D + nt*16 + quad*4) = v;
    }
}

extern "C" void kernel_launch(void* const* d_in, const int* in_sizes, int n_in,
                              void* d_out, int out_size, void* d_ws, size_t ws_size,
                              hipStream_t stream) {
    (void)d_ws; (void)ws_size; (void)n_in; (void)out_size;
    const float* x  = (const float*)d_in[0];
    const float* W1 = (const float*)d_in[1];
    const float* b1 = (const float*)d_in[2];
    const float* W2 = (const float*)d_in[3];
    const float* b2 = (const float*)d_in[4];
    const float* W3 = (const float*)d_in[5];
    const float* b3 = (const float*)d_in[6];
    float* out = (float*)d_out;

    const int n = in_sizes[0] / D;          // 65536 samples
    const int grid = n / 64;                // 1024 blocks (64 samples each), exact
    ffjord_mfma<<<grid, BT, 0, stream>>>(x, W1, b1, W2, b2, W3, b3, out);
}

// Round 11
// 746.955 us; speedup vs baseline: 1.4831x; 1.2169x over previous
//
#include <hip/hip_runtime.h>

#define NB 2
#define D 32
#define H 128
#define NSTEPS 8
#define BT 256

typedef _Float16 f16;
typedef _Float16 f16x2 __attribute__((ext_vector_type(2)));
typedef _Float16 f16x8 __attribute__((ext_vector_type(8)));
typedef float    f32x4 __attribute__((ext_vector_type(4)));
typedef unsigned int uint;

// Weights/biases feeding a tanh are pre-scaled by 2*log2(e) at staging time, so
// the MFMA accumulator is already v = 2*log2e*z and tanh needs no multiply:
#define TSCL 2.8853900817779268f

__device__ __forceinline__ float fast_tanh_pre(float v) {
    // v = 2*log2e*z. tanh(z) = 1 - 2/(1+2^v); exp2 saturates -> exact +-1 limits.
    float e = __builtin_amdgcn_exp2f(v);
    return 1.f - 2.f * __builtin_amdgcn_rcpf(1.f + e);
}
// tanh two pre-scaled f32 accs -> packed f16x2 dword
__device__ __forceinline__ uint tanh_pk(float a, float b) {
    return __builtin_bit_cast(uint, __builtin_amdgcn_cvt_pkrtz(fast_tanh_pre(a), fast_tanh_pre(b)));
}
__device__ __forceinline__ uint pku(float a, float b) {
    return __builtin_bit_cast(uint, __builtin_amdgcn_cvt_pkrtz(a, b));
}
__device__ __forceinline__ float lo32(uint u) { return (float)__builtin_bit_cast(f16x2, u)[0]; }
__device__ __forceinline__ float hi32(uint u) { return (float)__builtin_bit_cast(f16x2, u)[1]; }

__device__ const float CC[6] = {0.f, 0.2f, 0.3f, 0.8f, 8.f/9.f, 1.f};

// LDS: weights only, fragment-ordered & k-permuted. ~50 KB.
struct __align__(16) SMem {
    f16   W1f[8 * 64 * 8];     // [nt][lane][j]      : TSCL*W1[32+phi1(q,j)][nt*16+mr]
    f16   W2f[8 * 4 * 64 * 8]; // [nt][kt][lane][j]  : TSCL*W2[phi(kt,q,j)][nt*16+mr]
    f16   W3f[2 * 4 * 64 * 8]; // [nt][kt][lane][j]  : W3[phi(kt,q,j)][nt*16+mr] (unscaled)
    float B1[H], S1[H], B2[H], B3[D];   // B1,S1,B2 pre-scaled by TSCL
};

// phi(kt,q,j) = (2kt + j/4)*16 + q*4 + j%4 ; phi1(q,j) = (j/4)*16 + q*4 + j%4.
// Identical k-permutation on A (staged weights) and B (C-layout activations)
// -> MFMA k-sum invariant. Zero activation LDS traffic, zero shuffles.
//
// REGISTER/OCCUPANCY MODEL (measured R3..R10):
//  * per-SIMD VGPR pool = 512 unified; (256,2) -> 256/wave budget -> 128 arch,
//    2 waves/SIMD. Attempts at 3 waves/SIMD all spilled or starved:
//    (256,3) R6 full-unroll: 84 arch, 12 GB spill; R10 unroll-1: 68 arch,
//    2.1 GB spill-stores, occupancy stuck at 27%. (1024,8) R9: 32 arch, 3.8 GB.
//    (256,2)+unroll-1 (R8): VGPR=76, ZERO spill, 816 us. This is the stable point.
//  * nt-loops at `#pragma unroll 1` or 2 ONLY: full unroll hoists all
//    ds_read_b128 weight fragments (32 in flight = 128 VGPRs) -> GB-scale spill
//    (R4: 7.4 GB, R7: 7.6 GB). unroll 2 keeps <=2 iterations in flight (~8 regs).

__global__ __launch_bounds__(BT, 2) void ffjord_mfma(
    const float* __restrict__ x_in,
    const float* __restrict__ W1, const float* __restrict__ b1,
    const float* __restrict__ W2, const float* __restrict__ b2,
    const float* __restrict__ W3, const float* __restrict__ b3,
    float* __restrict__ out)
{
    __shared__ SMem sm;

    const int tid  = threadIdx.x;
    const int lane = tid & 63;
    const int mrow = lane & 15;      // my sample within the wave tile
    const int quad = lane >> 4;      // k/feature quad
    const int wid  = tid >> 6;
    const int sidx = blockIdx.x * 64 + wid * 16 + mrow;   // my sample (global)

    // Distributed state: x[nt*4 + r] = value[feature nt*16+quad*4+r][sample sidx]
    // k1..k5 packed f16x2: ksp[i][j] holds (elem 2j, 2j+1).
    float x[8];
    uint  ksp[5][4];
    uint  by[4];      // packed f16 y — layer-1 B fragment (IS the eval input)

    #pragma unroll
    for (int nt = 0; nt < 2; ++nt) {
        f32x4 v = *(const f32x4*)(x_in + (size_t)sidx*D + nt*16 + quad*4);
        #pragma unroll
        for (int r = 0; r < 4; ++r) x[nt*4 + r] = v[r];
    }

    const float dt = 0.125f;

    for (int bij = 0; bij < NB; ++bij) {
        const float* W1b = W1 + (size_t)bij * 2*D*H;
        const float* b1b = b1 + bij*H;
        const float* W2b = W2 + (size_t)bij * H*H;
        const float* b2b = b2 + bij*H;
        const float* W3b = W3 + (size_t)bij * H*D;
        const float* b3b = b3 + bij*D;

        __syncthreads();  // prior bijector done reading weights
        // ---- stage weights: fragment-order, k-permuted, f16, tanh-prescaled ----
        #pragma unroll 1
        for (int g = tid; g < 8*64; g += BT) {               // W1f (x TSCL)
            int nt = g >> 6, ln = g & 63, q = (ln >> 4) & 3, mr = ln & 15;
            f16 tmp[8];
            #pragma unroll
            for (int j = 0; j < 8; ++j) {
                int feat = ((j >> 2) << 4) + q*4 + (j & 3);  // phi1
                tmp[j] = (f16)(W1b[(size_t)(D + feat)*H + nt*16 + mr] * TSCL);
            }
            *(f16x8*)&sm.W1f[(size_t)g * 8] = *(f16x8*)tmp;
        }
        #pragma unroll 1
        for (int g = tid; g < 8*4*64; g += BT) {             // W2f (x TSCL)
            int nt = g >> 8, kt = (g >> 6) & 3, ln = g & 63, q = (ln >> 4) & 3, mr = ln & 15;
            f16 tmp[8];
            #pragma unroll
            for (int j = 0; j < 8; ++j) {
                int feat = (2*kt + (j >> 2))*16 + q*4 + (j & 3);  // phi
                tmp[j] = (f16)(W2b[(size_t)feat*H + nt*16 + mr] * TSCL);
            }
            *(f16x8*)&sm.W2f[(size_t)g * 8] = *(f16x8*)tmp;
        }
        #pragma unroll 1
        for (int g = tid; g < 2*4*64; g += BT) {             // W3f (unscaled)
            int nt = g >> 8, kt = (g >> 6) & 3, ln = g & 63, q = (ln >> 4) & 3, mr = ln & 15;
            f16 tmp[8];
            #pragma unroll
            for (int j = 0; j < 8; ++j) {
                int feat = (2*kt + (j >> 2))*16 + q*4 + (j & 3);  // phi
                tmp[j] = (f16)W3b[(size_t)feat*D + nt*16 + mr];
            }
            *(f16x8*)&sm.W3f[(size_t)g * 8] = *(f16x8*)tmp;
        }
        #pragma unroll 1
        for (int n = tid; n < H; n += BT) {                  // biases + t-fold sums (x TSCL)
            float s = 0.f;
            for (int i = 0; i < D; ++i) s += W1b[(size_t)i*H + n];
            sm.S1[n] = s * TSCL; sm.B1[n] = b1b[n] * TSCL; sm.B2[n] = b2b[n] * TSCL;
        }
        if (tid < D) sm.B3[tid] = b3b[tid];
        __syncthreads();

        // y := x  (packed)
        #pragma unroll
        for (int p = 0; p < 4; ++p)
            by[p] = pku(x[2*p], x[2*p + 1]);

        for (int step = 0; step < NSTEPS; ++step) {
            const float t0 = step * dt;
            #pragma unroll 1
            for (int s = 0; s < 6; ++s) {
                const float te = t0 + dt * CC[s];

                // ============ EVAL (registers + conflict-free weight LDS) ============
                // layer 1 (K=32): C init = (b1 + te*S1)*TSCL (t-concat + tanh scale folded)
                uint ph1[16];
                {
                    union { f16x8 v; uint u[4]; } b;
                    b.u[0] = by[0]; b.u[1] = by[1]; b.u[2] = by[2]; b.u[3] = by[3];
                    #pragma unroll 2
                    for (int nt = 0; nt < 8; ++nt) {
                        f16x8 wf = *(const f16x8*)&sm.W1f[(nt*64 + lane)*8];
                        f32x4 bv = *(const f32x4*)&sm.B1[nt*16 + quad*4];
                        f32x4 sv = *(const f32x4*)&sm.S1[nt*16 + quad*4];
                        f32x4 ci;
                        #pragma unroll
                        for (int r = 0; r < 4; ++r) ci[r] = fmaf(te, sv[r], bv[r]);
                        f32x4 acc = __builtin_amdgcn_mfma_f32_16x16x32_f16(wf, b.v, ci, 0, 0, 0);
                        ph1[nt*2+0] = tanh_pk(acc[0], acc[1]);
                        ph1[nt*2+1] = tanh_pk(acc[2], acc[3]);
                    }
                }
                // layer 2 (K=128): B = ph1 dwords (phi-matched)
                uint ph2[16];
                #pragma unroll 2
                for (int nt = 0; nt < 8; ++nt) {
                    f32x4 acc = *(const f32x4*)&sm.B2[nt*16 + quad*4];
                    #pragma unroll
                    for (int kt = 0; kt < 4; ++kt) {
                        f16x8 wf = *(const f16x8*)&sm.W2f[((nt*4 + kt)*64 + lane)*8];
                        union { f16x8 v; uint u[4]; } b;
                        b.u[0] = ph1[kt*4+0]; b.u[1] = ph1[kt*4+1];
                        b.u[2] = ph1[kt*4+2]; b.u[3] = ph1[kt*4+3];
                        acc = __builtin_amdgcn_mfma_f32_16x16x32_f16(wf, b.v, acc, 0, 0, 0);
                    }
                    ph2[nt*2+0] = tanh_pk(acc[0], acc[1]);
                    ph2[nt*2+1] = tanh_pk(acc[2], acc[3]);
                }
                // layer 3 (K=128, Nout=32): kd lands in distributed layout
                float kd[8];
                #pragma unroll 1
                for (int nt = 0; nt < 2; ++nt) {
                    f32x4 acc = *(const f32x4*)&sm.B3[nt*16 + quad*4];
                    #pragma unroll
                    for (int kt = 0; kt < 4; ++kt) {
                        f16x8 wf = *(const f16x8*)&sm.W3f[((nt*4 + kt)*64 + lane)*8];
                        union { f16x8 v; uint u[4]; } b;
                        b.u[0] = ph2[kt*4+0]; b.u[1] = ph2[kt*4+1];
                        b.u[2] = ph2[kt*4+2]; b.u[3] = ph2[kt*4+3];
                        acc = __builtin_amdgcn_mfma_f32_16x16x32_f16(wf, b.v, acc, 0, 0, 0);
                    }
                    #pragma unroll
                    for (int r = 0; r < 4; ++r) kd[nt*4 + r] = acc[r];
                }

                // ===== DOPRI combine; k-history packed f16, y kept only packed =====
                switch (s) {
                case 0:
                    #pragma unroll
                    for (int j = 0; j < 4; ++j) {
                        ksp[0][j] = pku(kd[2*j], kd[2*j+1]);
                        float ya = fmaf(dt*0.2f, kd[2*j],   x[2*j]);
                        float yb = fmaf(dt*0.2f, kd[2*j+1], x[2*j+1]);
                        by[j] = pku(ya, yb);
                    }
                    break;
                case 1:
                    #pragma unroll
                    for (int j = 0; j < 4; ++j) {
                        ksp[1][j] = pku(kd[2*j], kd[2*j+1]);
                        float ya = x[2*j]   + dt*((3.f/40.f)*lo32(ksp[0][j]) + (9.f/40.f)*kd[2*j]);
                        float yb = x[2*j+1] + dt*((3.f/40.f)*hi32(ksp[0][j]) + (9.f/40.f)*kd[2*j+1]);
                        by[j] = pku(ya, yb);
                    }
                    break;
                case 2:
                    #pragma unroll
                    for (int j = 0; j < 4; ++j) {
                        ksp[2][j] = pku(kd[2*j], kd[2*j+1]);
                        float ya = x[2*j]   + dt*((44.f/45.f)*lo32(ksp[0][j]) - (56.f/15.f)*lo32(ksp[1][j]) + (32.f/9.f)*kd[2*j]);
                        float yb = x[2*j+1] + dt*((44.f/45.f)*hi32(ksp[0][j]) - (56.f/15.f)*hi32(ksp[1][j]) + (32.f/9.f)*kd[2*j+1]);
                        by[j] = pku(ya, yb);
                    }
                    break;
                case 3:
                    #pragma unroll
                    for (int j = 0; j < 4; ++j) {
                        ksp[3][j] = pku(kd[2*j], kd[2*j+1]);
                        float ya = x[2*j]   + dt*((19372.f/6561.f)*lo32(ksp[0][j]) - (25360.f/2187.f)*lo32(ksp[1][j])
                                                + (64448.f/6561.f)*lo32(ksp[2][j]) - (212.f/729.f)*kd[2*j]);
                        float yb = x[2*j+1] + dt*((19372.f/6561.f)*hi32(ksp[0][j]) - (25360.f/2187.f)*hi32(ksp[1][j])
                                                + (64448.f/6561.f)*hi32(ksp[2][j]) - (212.f/729.f)*kd[2*j+1]);
                        by[j] = pku(ya, yb);
                    }
                    break;
                case 4:
                    #pragma unroll
                    for (int j = 0; j < 4; ++j) {
                        ksp[4][j] = pku(kd[2*j], kd[2*j+1]);
                        float ya = x[2*j]   + dt*((9017.f/3168.f)*lo32(ksp[0][j]) - (355.f/33.f)*lo32(ksp[1][j])
                                                + (46732.f/5247.f)*lo32(ksp[2][j]) + (49.f/176.f)*lo32(ksp[3][j])
                                                - (5103.f/18656.f)*kd[2*j]);
                        float yb = x[2*j+1] + dt*((9017.f/3168.f)*hi32(ksp[0][j]) - (355.f/33.f)*hi32(ksp[1][j])
                                                + (46732.f/5247.f)*hi32(ksp[2][j]) + (49.f/176.f)*hi32(ksp[3][j])
                                                - (5103.f/18656.f)*kd[2*j+1]);
                        by[j] = pku(ya, yb);
                    }
                    break;
                default:
                    #pragma unroll
                    for (int j = 0; j < 4; ++j) {
                        float xa = x[2*j]   + dt*((35.f/384.f)*lo32(ksp[0][j]) + (500.f/1113.f)*lo32(ksp[2][j])
                                                + (125.f/192.f)*lo32(ksp[3][j]) - (2187.f/6784.f)*lo32(ksp[4][j])
                                                + (11.f/84.f)*kd[2*j]);
                        float xb = x[2*j+1] + dt*((35.f/384.f)*hi32(ksp[0][j]) + (500.f/1113.f)*hi32(ksp[2][j])
                                                + (125.f/192.f)*hi32(ksp[3][j]) - (2187.f/6784.f)*hi32(ksp[4][j])
                                                + (11.f/84.f)*kd[2*j+1]);
                        x[2*j] = xa; x[2*j+1] = xb;
                        by[j] = pku(xa, xb);
                    }
                    break;
                }
            } // stages
        } // steps
    } // bijectors

    #pragma unroll
    for (int nt = 0; nt < 2; ++nt) {
        f32x4 v;
        #pragma unroll
        for (int r = 0; r < 4; ++r) v[r] = x[nt*4 + r];
        *(f32x4*)(out + (size_t)sidx*D + nt*16 + quad*4) = v;
    }
}

extern "C" void kernel_launch(void* const* d_in, const int* in_sizes, int n_in,
                              void* d_out, int out_size, void* d_ws, size_t ws_size,
                              hipStream_t stream) {
    (void)d_ws; (void)ws_size; (void)n_in; (void)out_size;
    const float* x  = (const float*)d_in[0];
    const float* W1 = (const float*)d_in[1];
    const float* b1 = (const float*)d_in[2];
    const float* W2 = (const float*)d_in[3];
    const float* b2 = (const float*)d_in[4];
    const float* W3 = (const float*)d_in[5];
    const float* b3 = (const float*)d_in[6];
    float* out = (float*)d_out;

    const int n = in_sizes[0] / D;          // 65536 samples
    const int grid = n / 64;                // 1024 blocks (64 samples each), exact
    ffjord_mfma<<<grid, BT, 0, stream>>>(x, W1, b1, W2, b2, W3, b3, out);
}